// Round 1
// baseline (7894.978 us; speedup 1.0000x reference)
//
#include <hip/hip_runtime.h>

// TruncatedHistoryAttn on MI355X.
// B=32 independent recurrences, S=512 steps, D=512, history=5.
// Design:
//  - Per history entry, h@W1 and tilde@W3 are computed ONCE (when the entry is
//    created) and kept in rolling buffers -> 3 matvecs/step/batch total.
//  - 8 WGs per batch (grid 256 x 512 thr, 1 WG/CU). Each WG holds a 64-column
//    slice of W1,W2,W3 in registers (3*64 = 192 VGPRs) -> zero weight traffic
//    in the steady state.
//  - Per step, each WG redundantly computes temp/softmax/tilde for its batch;
//    the distributed matvec slices (ac = h@W1 + tilde@W3, and b=h@W2 for the
//    NEXT step) are exchanged via a double-buffered global buffer with one
//    agent-scope release/acquire counter round per step.
// ws: ybuf[2][B][2][D] floats (256KB) + cnt[B] uint (zeroed via memsetAsync).

#define BB   32
#define SS   512
#define DD   512
#define NS   5
#define KWG  8     // workgroups per batch
#define COLS 64    // DD / KWG
#define NTHR 512

static_assert(DD == NTHR, "one thread per dim");

__device__ __forceinline__ float fast_tanh(float x) {
  float e = __expf(2.0f * x);
  return 1.0f - 2.0f / (e + 1.0f);
}

// 64-long dot: base is LDS (wave-broadcast reads), w is a register array.
__device__ __forceinline__ float dot64(const float* base, const float* w) {
  float a0 = 0.f, a1 = 0.f, a2 = 0.f, a3 = 0.f;
#pragma unroll
  for (int i = 0; i < 16; ++i) {
    float4 tv = ((const float4*)base)[i];
    a0 = fmaf(tv.x, w[4 * i + 0], a0);
    a1 = fmaf(tv.y, w[4 * i + 1], a1);
    a2 = fmaf(tv.z, w[4 * i + 2], a2);
    a3 = fmaf(tv.w, w[4 * i + 3], a3);
  }
  return (a0 + a1) + (a2 + a3);
}

__global__ void __launch_bounds__(NTHR, 2)
thattn_kernel(const float* __restrict__ H, const float* __restrict__ v,
              const float* __restrict__ W1, const float* __restrict__ W2,
              const float* __restrict__ W3, float* __restrict__ out,
              float* __restrict__ ybuf, unsigned int* __restrict__ cnt) {
  const int tid = threadIdx.x;
  const int bid = blockIdx.x;
  const int b   = bid & (BB - 1);   // batch: WGs of batch b are b, b+32, ... (same XCD mod 8)
  const int g   = bid >> 5;         // column-slice group 0..7
  const int q   = tid >> 6;         // k-chunk 0..7 (== wave id)
  const int c   = tid & 63;         // lane / column-in-slice
  const int col = g * COLS + c;

  __shared__ float ht_lds[DD];       // h_t row (for y1 = h_t @ W1)
  __shared__ float htn_lds[DD];      // h_{t+1} row (for y2 = h_{t+1} @ W2)
  __shared__ float tilde_cur[DD];    // tilde_t row (for y3 = tilde_t @ W3)
  __shared__ float ac_hist[NS][DD];  // rolling: h_s@W1 + tilde_s@W3, slot s%5
  __shared__ float tl_hist[NS][DD];  // rolling: tilde_s, slot s%5
  __shared__ float wred[8][8];       // per-wave score partials [wave][j]
  __shared__ float w_sm[NS];         // softmax weights
  __shared__ float mv[2][8][COLS];   // matvec partials [part][q][c]

  // zero-init history rings (column-private: thread d owns column d)
#pragma unroll
  for (int j = 0; j < NS; ++j) { ac_hist[j][tid] = 0.f; tl_hist[j][tid] = 0.f; }

  // persistent weight slices in registers: w[kk] = W[(q*64+kk)][col]
  float w1r[64], w2r[64], w3r[64];
  {
    const float* p1 = W1 + (q * 64) * DD + col;
    const float* p2 = W2 + (q * 64) * DD + col;
    const float* p3 = W3 + (q * 64) * DD + col;
#pragma unroll
    for (int kk = 0; kk < 64; ++kk) {
      w1r[kk] = p1[kk * DD];
      w2r[kk] = p2[kk * DD];
      w3r[kk] = p3[kk * DD];
    }
  }
  const float v_d = v[tid];

  float* ybuf_b = ybuf + b * 2 * DD;  // + slot*(BB*2*DD) + part*DD + d
  unsigned int* cb = cnt + b;

  // ---- prologue (round 0): y2 for row 0 -> slot 0, part 1
  ht_lds[tid] = H[(b * SS + 0) * DD + tid];
  __syncthreads();
  mv[1][q][c] = dot64(ht_lds + q * 64, w2r);
  __syncthreads();
  if (tid < 64) {
    float ssum = 0.f;
#pragma unroll
    for (int qq = 0; qq < 8; ++qq) ssum += mv[1][qq][tid];
    __hip_atomic_store(&ybuf_b[0 * (BB * 2 * DD) + 1 * DD + g * COLS + tid], ssum,
                       __ATOMIC_RELAXED, __HIP_MEMORY_SCOPE_AGENT);
  }
  __syncthreads();
  if (tid == 0) {
    __threadfence();
    __hip_atomic_fetch_add(cb, 1u, __ATOMIC_RELEASE, __HIP_MEMORY_SCOPE_AGENT);
  }

  // ---- main loop: round r = t+1
  for (int t = 0; t < SS; ++t) {
    const int r = t + 1;
    if (tid == 0) {
      // wait until all 8 WGs of this batch finished round r-1
      while (__hip_atomic_load(cb, __ATOMIC_ACQUIRE, __HIP_MEMORY_SCOPE_AGENT) <
             (unsigned)(KWG * r)) { }
    }
    __syncthreads();

    const int slotR = (r - 1) & 1;
    // b_t = h_t @ W2 (produced last round); atomic loads bypass L1.
    float b_t = __hip_atomic_load(&ybuf_b[slotR * (BB * 2 * DD) + 1 * DD + tid],
                                  __ATOMIC_RELAXED, __HIP_MEMORY_SCOPE_AGENT);
    if (t >= 1) {
      float ac = __hip_atomic_load(&ybuf_b[slotR * (BB * 2 * DD) + 0 * DD + tid],
                                   __ATOMIC_RELAXED, __HIP_MEMORY_SCOPE_AGENT);
      ac_hist[(t - 1) % NS][tid] = ac;  // slot for history step t-1
    }
    float h_d = H[(b * SS + t) * DD + tid];
    ht_lds[tid] = h_d;
    if (t + 1 < SS) htn_lds[tid] = H[(b * SS + t + 1) * DD + tid];

    // temp_j = tanh(a_j + b_t + c_j); score partial = temp_j * v[d]
    float s[NS];
#pragma unroll
    for (int j = 0; j < NS; ++j) {
      float a = ac_hist[(t + j) % NS][tid];  // == slot (t-5+j)%5; zeros for s<0
      s[j] = fast_tanh(a + b_t) * v_d;
    }
    // wave reduction (64 lanes), then cross-wave via LDS
#pragma unroll
    for (int j = 0; j < NS; ++j) {
      float val = s[j];
#pragma unroll
      for (int off = 32; off >= 1; off >>= 1) val += __shfl_xor(val, off, 64);
      s[j] = val;
    }
    if (c == 0) {
#pragma unroll
      for (int j = 0; j < NS; ++j) wred[q][j] = s[j];
    }
    __syncthreads();
    if (tid == 0) {
      float sc[NS];
#pragma unroll
      for (int j = 0; j < NS; ++j) {
        float ssum = 0.f;
#pragma unroll
        for (int qq = 0; qq < 8; ++qq) ssum += wred[qq][j];
        sc[j] = ssum;
      }
      float m = sc[0];
#pragma unroll
      for (int j = 1; j < NS; ++j) m = fmaxf(m, sc[j]);
      float es = 0.f;
#pragma unroll
      for (int j = 0; j < NS; ++j) { sc[j] = __expf(sc[j] - m); es += sc[j]; }
      float inv = 1.0f / es;
#pragma unroll
      for (int j = 0; j < NS; ++j) w_sm[j] = sc[j] * inv;
    }
    __syncthreads();

    // ht_hat, tilde
    float hh = 0.f;
#pragma unroll
    for (int j = 0; j < NS; ++j) hh = fmaf(w_sm[j], tl_hist[(t + j) % NS][tid], hh);
    float tld = h_d + fmaxf(hh, 0.f);
    tl_hist[t % NS][tid] = tld;   // slot t%5 (old entry t-5 already consumed)
    tilde_cur[tid] = tld;
    if (g == 0) out[(b * SS + t) * DD + tid] = tld;
    __syncthreads();

    // distributed matvecs from register-resident weight slices
    float a3 = dot64(tilde_cur + q * 64, w3r);  // tilde_t @ W3  (recurrent)
    float a1 = dot64(ht_lds    + q * 64, w1r);  // h_t @ W1      (for future ac)
    float a2 = dot64(htn_lds   + q * 64, w2r);  // h_{t+1} @ W2  (next step's b)
    mv[0][q][c] = a1 + a3;
    mv[1][q][c] = a2;
    __syncthreads();
    const int slotW = r & 1;
    if (tid < 128) {
      const int part = tid >> 6;
      const int cc   = tid & 63;
      float ssum = 0.f;
#pragma unroll
      for (int qq = 0; qq < 8; ++qq) ssum += mv[part][qq][cc];
      __hip_atomic_store(&ybuf_b[slotW * (BB * 2 * DD) + part * DD + g * COLS + cc],
                         ssum, __ATOMIC_RELAXED, __HIP_MEMORY_SCOPE_AGENT);
    }
    __syncthreads();
    if (tid == 0) {
      __threadfence();
      __hip_atomic_fetch_add(cb, 1u, __ATOMIC_RELEASE, __HIP_MEMORY_SCOPE_AGENT);
    }
  }
}

extern "C" void kernel_launch(void* const* d_in, const int* in_sizes, int n_in,
                              void* d_out, int out_size, void* d_ws, size_t ws_size,
                              hipStream_t stream) {
  const float* H  = (const float*)d_in[0];
  const float* v  = (const float*)d_in[1];
  const float* W1 = (const float*)d_in[2];
  const float* W2 = (const float*)d_in[3];
  const float* W3 = (const float*)d_in[4];
  float* out = (float*)d_out;

  float* ybuf = (float*)d_ws;                                    // 2*B*2*D floats
  unsigned int* cnt =
      (unsigned int*)((char*)d_ws + (size_t)2 * BB * 2 * DD * sizeof(float));

  hipMemsetAsync(cnt, 0, BB * sizeof(unsigned int), stream);
  hipLaunchKernelGGL(thattn_kernel, dim3(BB * KWG), dim3(NTHR), 0, stream,
                     H, v, W1, W2, W3, out, ybuf, cnt);
}

// Round 3
// 4850.085 us; speedup vs baseline: 1.6278x; 1.6278x over previous
//
#include <hip/hip_runtime.h>

// TruncatedHistoryAttn, round 3 (round-2 design, compile fixes only).
// Phase 1: fp32 tiled GEMM  A = H@W1 (-> ws), B2 = H@W2 (-> d_out, reused).
// Phase 2: 4 WGs/batch recurrence; only W3 register-resident (128 f/thread,
//          asm-pinned); history rows live in per-thread register rings
//          (5-unrolled time loop -> compile-time ring indices); per-batch
//          flag quad on its own 256B line, relaxed polls + acquire fence.

#define BB 32
#define SS 512
#define DD 512
#define NS 5

#define A_ELEMS    ((size_t)BB * SS * DD)          // 8388608 floats (32 MB)
#define YBUF_ELEMS ((size_t)2 * BB * DD)           // 32768 floats (128 KB)
#define FLAGS_OFF  ((A_ELEMS + YBUF_ELEMS) * 4)    // bytes
#define FLAGS_BYTES ((size_t)BB * 64 * 4)          // 8 KB (256B stride/batch)
#define WS_NEED    (FLAGS_OFF + FLAGS_BYTES)

// ---------------- Phase 1: A = H@W1, B2 = H@W2 (fp32) ----------------
// M=16384, N=512, K=512. 64x64 tiles, 256 thr, 4x4 per thread per output.
__global__ void __launch_bounds__(256) th_phase1(
    const float* __restrict__ H, const float* __restrict__ W1,
    const float* __restrict__ W2, float* __restrict__ A, float* __restrict__ B2) {
  const int tid = threadIdx.x;
  const int mt = blockIdx.x >> 3;
  const int nt = blockIdx.x & 7;
  const int m0 = mt << 6, n0 = nt << 6;
  __shared__ float Ht[64][20];   // padded: 20 % 4 == 0 keeps f4 align, breaks conflicts
  __shared__ float Wt1[16][64];
  __shared__ float Wt2[16][64];
  const int tx = tid & 15, ty = tid >> 4;
  const int sr = tid >> 2, sk = (tid & 3) << 2;   // H staging: 64 rows x 16k
  const int wr = tid >> 4, wn = (tid & 15) << 2;  // W staging: 16 rows x 64n
  float a1[4][4] = {{0.f}}, a2[4][4] = {{0.f}};

  for (int k0 = 0; k0 < DD; k0 += 16) {
    float4 hv  = *(const float4*)&H[(size_t)(m0 + sr) * DD + k0 + sk];
    float4 w1v = *(const float4*)&W1[(size_t)(k0 + wr) * DD + n0 + wn];
    float4 w2v = *(const float4*)&W2[(size_t)(k0 + wr) * DD + n0 + wn];
    *(float4*)&Ht[sr][sk]  = hv;
    *(float4*)&Wt1[wr][wn] = w1v;
    *(float4*)&Wt2[wr][wn] = w2v;
    __syncthreads();
#pragma unroll
    for (int kq = 0; kq < 16; kq += 4) {
      float hs[4][4];
#pragma unroll
      for (int i = 0; i < 4; ++i) {
        float4 h4 = *(const float4*)&Ht[ty * 4 + i][kq];
        hs[i][0] = h4.x; hs[i][1] = h4.y; hs[i][2] = h4.z; hs[i][3] = h4.w;
      }
#pragma unroll
      for (int kk = 0; kk < 4; ++kk) {
        float4 w1f = *(const float4*)&Wt1[kq + kk][tx * 4];
        float4 w2f = *(const float4*)&Wt2[kq + kk][tx * 4];
#pragma unroll
        for (int i = 0; i < 4; ++i) {
          float h = hs[i][kk];
          a1[i][0] = fmaf(h, w1f.x, a1[i][0]);
          a1[i][1] = fmaf(h, w1f.y, a1[i][1]);
          a1[i][2] = fmaf(h, w1f.z, a1[i][2]);
          a1[i][3] = fmaf(h, w1f.w, a1[i][3]);
          a2[i][0] = fmaf(h, w2f.x, a2[i][0]);
          a2[i][1] = fmaf(h, w2f.y, a2[i][1]);
          a2[i][2] = fmaf(h, w2f.z, a2[i][2]);
          a2[i][3] = fmaf(h, w2f.w, a2[i][3]);
        }
      }
    }
    __syncthreads();
  }
#pragma unroll
  for (int i = 0; i < 4; ++i) {
    float4 o1 = make_float4(a1[i][0], a1[i][1], a1[i][2], a1[i][3]);
    float4 o2 = make_float4(a2[i][0], a2[i][1], a2[i][2], a2[i][3]);
    size_t off = (size_t)(m0 + ty * 4 + i) * DD + n0 + tx * 4;
    *(float4*)&A[off]  = o1;
    *(float4*)&B2[off] = o2;
  }
}

// ---------------- Phase 2: the recurrence ----------------
// grid 128 = 4 WGs/batch; bid = g*32+b so a batch's WGs share an XCD (mod-8).
__global__ void __launch_bounds__(512, 2) th_phase2(
    const float* __restrict__ H, const float* __restrict__ v,
    const float* __restrict__ W3, const float* __restrict__ A,
    float* __restrict__ Ob,  // d_out: holds B2, overwritten with tilde rows
    float* __restrict__ ybuf, unsigned int* __restrict__ flags) {
  const int tid = threadIdx.x;
  const int b = blockIdx.x & 31;
  const int g = blockIdx.x >> 5;
  const int seg = tid >> 7;       // k-segment 0..3 (matvec layout)
  const int cc  = tid & 127;      // column within WG slice
  const int col = (g << 7) + cc;  // this WG owns cols [g*128, g*128+128)

  __shared__ float tlds[DD];      // tilde_t row for the matvec
  __shared__ float pm[DD];        // matvec partials
  __shared__ float wred[8][NS];   // per-wave score partials
  __shared__ float wsm[NS];       // softmax weights

  // W3 slice: w[kk] = W3[seg*128+kk][col]; asm-pin so the compiler cannot
  // rematerialize the global loads inside the loop (round-1 failure mode).
  float w[128];
#pragma unroll
  for (int kk = 0; kk < 128; ++kk)
    w[kk] = W3[(size_t)(seg * 128 + kk) * DD + col];
#pragma unroll
  for (int kk = 0; kk < 128; ++kk) asm volatile("" : "+v"(w[kk]));

  const float v_d = v[tid];
  // per-thread register rings, slot = step mod 5 (compile-time via 5-unroll)
  float aA[NS] = {0.f, 0.f, 0.f, 0.f, 0.f};  // h_s @ W1
  float cC[NS] = {0.f, 0.f, 0.f, 0.f, 0.f};  // tilde_s @ W3
  float tl[NS] = {0.f, 0.f, 0.f, 0.f, 0.f};  // tilde_s
  float tld_prev = 0.f;

  const float* Hb = H + (size_t)b * SS * DD;
  const float* Ab = A + (size_t)b * SS * DD;
  float* Op = Ob + (size_t)b * SS * DD;
  float* yb = ybuf + (size_t)b * DD;  // + slot*BB*DD + d
  unsigned int* fb = flags + b * 64;  // 4 flags, own 256B line

  for (int t5 = 0; t5 < 515; t5 += 5) {
#pragma unroll
    for (int p = 0; p < NS; ++p) {
      const int t = t5 + p;
      if (t < SS) {
        // prefetch (independent of the poll)
        float h_d = Hb[(size_t)t * DD + tid];
        float bt  = Op[(size_t)t * DD + tid];  // B2[b][t]
        float aNew = 0.f, cNew = 0.f;
        if (t >= 1) {
          aNew = Ab[(size_t)(t - 1) * DD + tid];
          if (tid == 0) {
            for (;;) {
              unsigned f0 = __hip_atomic_load(&fb[0], __ATOMIC_RELAXED, __HIP_MEMORY_SCOPE_AGENT);
              unsigned f1 = __hip_atomic_load(&fb[1], __ATOMIC_RELAXED, __HIP_MEMORY_SCOPE_AGENT);
              unsigned f2 = __hip_atomic_load(&fb[2], __ATOMIC_RELAXED, __HIP_MEMORY_SCOPE_AGENT);
              unsigned f3 = __hip_atomic_load(&fb[3], __ATOMIC_RELAXED, __HIP_MEMORY_SCOPE_AGENT);
              if (f0 >= (unsigned)t && f1 >= (unsigned)t && f2 >= (unsigned)t &&
                  f3 >= (unsigned)t)
                break;
            }
          }
          __syncthreads();
          __builtin_amdgcn_fence(__ATOMIC_ACQUIRE, "agent");
          cNew = __hip_atomic_load(&yb[(size_t)((t - 1) & 1) * BB * DD + tid],
                                   __ATOMIC_RELAXED, __HIP_MEMORY_SCOPE_AGENT);
          // deferred out-write: all sibling WGs finished step t-1, so B2 row
          // t-1 is dead -> safe to overwrite with tilde_{t-1}.
          if (g == 0) Op[(size_t)(t - 1) * DD + tid] = tld_prev;
        }
        aA[(p + 4) % NS] = aNew;  // entrant s = t-1
        cC[(p + 4) % NS] = cNew;

        // scores: s_j = tanh(a_j + b_t + c_j) * v_d, reduced over d
        float sj[NS];
#pragma unroll
        for (int j = 0; j < NS; ++j) {
          float x = aA[(p + j) % NS] + bt + cC[(p + j) % NS];
          float e = __expf(2.0f * x);
          sj[j] = (1.0f - 2.0f / (e + 1.0f)) * v_d;
        }
#pragma unroll
        for (int j = 0; j < NS; ++j) {
#pragma unroll
          for (int off = 32; off >= 1; off >>= 1) sj[j] += __shfl_xor(sj[j], off, 64);
        }
        if ((tid & 63) == 0) {
          const int q = tid >> 6;
#pragma unroll
          for (int j = 0; j < NS; ++j) wred[q][j] = sj[j];
        }
        __syncthreads();
        if (tid == 0) {
          float sc[NS];
#pragma unroll
          for (int j = 0; j < NS; ++j) {
            float s = 0.f;
#pragma unroll
            for (int q = 0; q < 8; ++q) s += wred[q][j];
            sc[j] = s;
          }
          float mx = sc[0];
#pragma unroll
          for (int j = 1; j < NS; ++j) mx = fmaxf(mx, sc[j]);
          float es = 0.f;
#pragma unroll
          for (int j = 0; j < NS; ++j) { sc[j] = __expf(sc[j] - mx); es += sc[j]; }
          float inv = 1.0f / es;
#pragma unroll
          for (int j = 0; j < NS; ++j) wsm[j] = sc[j] * inv;
        }
        __syncthreads();

        float hh = 0.f;
#pragma unroll
        for (int j = 0; j < NS; ++j) hh = fmaf(wsm[j], tl[(p + j) % NS], hh);
        float tld = h_d + fmaxf(hh, 0.f);
        tl[p] = tld;  // entrant s = t (old slot p held s = t-5, consumed above)
        tlds[tid] = tld;
        __syncthreads();

        // c_t slice: this WG's 128 cols, k split 4 ways across thread segs
        float q0 = 0.f, q1 = 0.f, q2 = 0.f, q3 = 0.f;
        const float4* tv = (const float4*)&tlds[seg << 7];
#pragma unroll
        for (int i = 0; i < 32; ++i) {
          float4 t4 = tv[i];
          q0 = fmaf(t4.x, w[4 * i + 0], q0);
          q1 = fmaf(t4.y, w[4 * i + 1], q1);
          q2 = fmaf(t4.z, w[4 * i + 2], q2);
          q3 = fmaf(t4.w, w[4 * i + 3], q3);
        }
        pm[tid] = (q0 + q1) + (q2 + q3);
        __syncthreads();
        if (tid < 128) {
          float cs = pm[tid] + pm[128 + tid] + pm[256 + tid] + pm[384 + tid];
          __hip_atomic_store(&yb[(size_t)(t & 1) * BB * DD + (g << 7) + tid], cs,
                             __ATOMIC_RELAXED, __HIP_MEMORY_SCOPE_AGENT);
        }
        __syncthreads();  // drains vmcnt for all waves before the release
        if (tid == 0)
          __hip_atomic_store(&fb[g], (unsigned)(t + 1), __ATOMIC_RELEASE,
                             __HIP_MEMORY_SCOPE_AGENT);
        tld_prev = tld;
      }
    }
  }
  if (g == 0) Op[(size_t)(SS - 1) * DD + tid] = tld_prev;
}

extern "C" void kernel_launch(void* const* d_in, const int* in_sizes, int n_in,
                              void* d_out, int out_size, void* d_ws, size_t ws_size,
                              hipStream_t stream) {
  const float* H  = (const float*)d_in[0];
  const float* v  = (const float*)d_in[1];
  const float* W1 = (const float*)d_in[2];
  const float* W2 = (const float*)d_in[3];
  const float* W3 = (const float*)d_in[4];
  float* out = (float*)d_out;

  if (ws_size < WS_NEED) return;  // clean failure signal (absmax), no crash

  float* A    = (float*)d_ws;
  float* ybuf = A + A_ELEMS;
  unsigned int* flags = (unsigned int*)((char*)d_ws + FLAGS_OFF);

  (void)hipMemsetAsync(flags, 0, FLAGS_BYTES, stream);
  hipLaunchKernelGGL(th_phase1, dim3(256 * 8), dim3(256), 0, stream,
                     H, W1, W2, A, out);
  hipLaunchKernelGGL(th_phase2, dim3(BB * 4), dim3(512), 0, stream,
                     H, v, W3, A, out, ybuf, flags);
}